// Round 1
// baseline (252.215 us; speedup 1.0000x reference)
//
#include <hip/hip_runtime.h>

// EIT3Attention: B=4, Sq=Sk=2048, d_model=2048, H=16, Dh=128, fp32 I/O.
// int4 quant-dequant on K/V (scale 0.05, zp 8), mask all-true, causal disabled.
//
// Round-1 design: 8-wave (512 thr) flash attention, Q-tile 256 (32/wave),
// KVBLK=64, swapped QK^T (mfma(Kd, Q) -> S^T so softmax is lane-local),
// cvt_pk_bf16 + permlane32_swap to build P A-frags in-register,
// K in XOR-swizzled LDS, V in subtiled LDS consumed via ds_read_b64_tr_b16.

typedef __attribute__((ext_vector_type(8))) short short8;
typedef __attribute__((ext_vector_type(16))) float f32x16;

#define DEVI __device__ __forceinline__

namespace {

constexpr int DM = 2048;   // d_model
constexpr int SQ = 2048;
constexpr int SK = 2048;
constexpr int DH = 128;
// (1/sqrt(128)) * log2(e)
constexpr float CEXP = 0.12752051393f;

union US8 { unsigned short u[8]; short8 v; };
union UV2 { unsigned long long q[2]; short8 v; };
union UP4 { unsigned int u[4]; short8 v; };

DEVI unsigned short f2bf(float f) {            // fp32 -> bf16 RNE
  unsigned int u = __float_as_uint(f);
  return (unsigned short)((u + 0x7fffu + ((u >> 16) & 1u)) >> 16);
}

DEVI float dq(float x) {                       // int4 quant-dequant, matches ref
  float t = __builtin_rintf(__builtin_fmaf(x, 20.0f, 8.0f));  // round half-even
  t = __builtin_fmaxf(t, 0.0f);
  t = __builtin_fminf(t, 15.0f);
  return (t - 8.0f) * 0.05f;
}

DEVI unsigned short dqb(float x) { return f2bf(dq(x)); }

} // namespace

__global__ __launch_bounds__(512, 2)
void eit3_attn(const float* __restrict__ qg, const float* __restrict__ kg,
               const float* __restrict__ vg, const unsigned char* __restrict__ maskg,
               const int* __restrict__ qsg, float* __restrict__ outg)
{
  const int tid  = threadIdx.x;
  const int lane = tid & 63;
  const int w    = tid >> 6;        // wave 0..7
  const int hi   = lane >> 5;       // 0/1 half of wave
  const int ql   = lane & 31;       // q column (S^T) / k row (A-frag) / d col (out)
  const int qb = blockIdx.x;        // 0..7  (q tile of 256)
  const int h  = blockIdx.y;        // 0..15
  const int b  = blockIdx.z;        // 0..3
  const int q0 = qb * 256;
  const long long qstart = (long long)qsg[0];

  __shared__ __align__(16) unsigned short Ksh[64 * 128]; // swizzled row-major bf16
  __shared__ __align__(16) unsigned short Vsh[64 * 128]; // subtiled [k/4][d/16][4][16]
  __shared__ unsigned char mskSh[64];

  const unsigned int vbase = (unsigned int)(size_t)(void*)Vsh;

  // ---- robust mask all-true check for this batch row (handles u8 or i32 bool) ----
  const unsigned char* mrow = maskg + (size_t)b * SK;
  int ok_u8, ok_i32;
  {
    const unsigned char* p4 = mrow + tid * 4;   // 512 thr x 4B = 2048B
    unsigned char b0 = p4[0], b1 = p4[1], b2 = p4[2], b3 = p4[3];
    ok_u8  = (b0 && b1 && b2 && b3);
    ok_i32 = (b0 && !b1 && !b2 && !b3);         // little-endian int32 == 1 pattern
  }
  const int a_u8  = __syncthreads_and(ok_u8);
  const int a_i32 = __syncthreads_and(ok_i32);
  const bool mask_all = (a_u8 | a_i32) != 0;

  // ---- load Q fragments (B-operand of swapped QK^T): lane holds Q[q][16s+8hi+i] ----
  short8 qf[8];
  {
    const int qrow = q0 + w * 32 + ql;
    const float* qp = qg + ((size_t)b * SQ + qrow) * DM + h * DH + hi * 8;
#pragma unroll
    for (int s = 0; s < 8; ++s) {
      float4 fa = *(const float4*)(qp + s * 16);
      float4 fb = *(const float4*)(qp + s * 16 + 4);
      US8 t;
      t.u[0] = f2bf(fa.x); t.u[1] = f2bf(fa.y); t.u[2] = f2bf(fa.z); t.u[3] = f2bf(fa.w);
      t.u[4] = f2bf(fb.x); t.u[5] = f2bf(fb.y); t.u[6] = f2bf(fb.z); t.u[7] = f2bf(fb.w);
      qf[s] = t.v;
    }
  }

  f32x16 zv;
#pragma unroll
  for (int r = 0; r < 16; ++r) zv[r] = 0.0f;
  f32x16 acc[4];
  acc[0] = zv; acc[1] = zv; acc[2] = zv; acc[3] = zv;
  float M = -3.0e38f, L = 0.0f;

  const float* kptr = kg + ((size_t)b * SK) * DM + h * DH;
  const float* vptr = vg + ((size_t)b * SK) * DM + h * DH;

  for (int kv0 = 0; kv0 < SK; kv0 += 64) {
    __syncthreads();  // previous tile's LDS reads complete before overwrite

    // ---- stage K: dequant->bf16, row-major [64][128], byte ^= (row&7)<<4 swizzle ----
#pragma unroll
    for (int j = 0; j < 2; ++j) {
      int idx = tid + 512 * j;
      int n = idx >> 4, d8 = idx & 15;
      const float* gp = kptr + (size_t)(kv0 + n) * DM + d8 * 8;
      float4 fa = *(const float4*)gp;
      float4 fb = *(const float4*)(gp + 4);
      US8 t;
      t.u[0] = dqb(fa.x); t.u[1] = dqb(fa.y); t.u[2] = dqb(fa.z); t.u[3] = dqb(fa.w);
      t.u[4] = dqb(fb.x); t.u[5] = dqb(fb.y); t.u[6] = dqb(fb.z); t.u[7] = dqb(fb.w);
      int ui = (n * 128 + d8 * 8) ^ ((n & 7) << 3);   // element-index XOR (16B granule)
      *(short8*)(Ksh + ui) = t.v;
    }

    // ---- stage V: dequant->bf16, subtiled [k>>2][d>>4][k&3][d&15] for tr_b16 reads ----
    {
      int kr = w * 8 + (lane & 7);
      int c3 = lane >> 3;
#pragma unroll
      for (int j = 0; j < 4; ++j) {
        int d4 = c3 + 8 * j;
        const float* gp = vptr + (size_t)(kv0 + kr) * DM + d4 * 4;
        float4 fa = *(const float4*)gp;
        ushort4 tv;
        tv.x = dqb(fa.x); tv.y = dqb(fa.y); tv.z = dqb(fa.z); tv.w = dqb(fa.w);
        int d = d4 * 4;
        int ui = ((kr >> 2) * 8 + (d >> 4)) * 64 + (kr & 3) * 16 + (d & 15);
        *(ushort4*)(Vsh + ui) = tv;
      }
    }

    const bool causal_ok = ((long long)kv0 + 63) <= (qstart + (long long)q0);
    const bool fast = mask_all && causal_ok;
    if (!fast && w == 0) mskSh[lane] = mrow[kv0 + lane];

    __syncthreads();

    // ---- QK^T (swapped): S^T[k][q] += Kd[k][d] * Q[q][d] ----
    f32x16 st[2];
#pragma unroll
    for (int t = 0; t < 2; ++t) {
      f32x16 sa = zv;
#pragma unroll
      for (int s = 0; s < 8; ++s) {
        int kr = t * 32 + ql;
        int ui = (kr * 128 + s * 16 + hi * 8) ^ ((kr & 7) << 3);
        short8 af = *(const short8*)(Ksh + ui);
        sa = __builtin_amdgcn_mfma_f32_32x32x16_bf16(af, qf[s], sa, 0, 0, 0);
      }
      st[t] = sa;
    }

    // ---- mask / causal (slow path only; bench takes fast path) ----
    if (!fast) {
      const long long qlim = qstart + (long long)(q0 + w * 32 + ql);
#pragma unroll
      for (int t = 0; t < 2; ++t) {
#pragma unroll
        for (int r = 0; r < 16; ++r) {
          int nl = t * 32 + (r & 3) + 8 * (r >> 2) + 4 * hi;
          bool ok = (mskSh[nl] != 0) && ((long long)(kv0 + nl) <= qlim);
          if (!ok) st[t][r] = -3.0e38f;
        }
      }
    }

    // ---- online softmax: per-lane q column; pair (lane, lane^32) covers 64 k ----
    f32x16 red;
#pragma unroll
    for (int r = 0; r < 16; ++r) red[r] = __builtin_fmaxf(st[0][r], st[1][r]);
#pragma unroll
    for (int r = 0; r < 8; ++r) red[r] = __builtin_fmaxf(red[r], red[r + 8]);
#pragma unroll
    for (int r = 0; r < 4; ++r) red[r] = __builtin_fmaxf(red[r], red[r + 4]);
    float pmax = __builtin_fmaxf(__builtin_fmaxf(red[0], red[1]),
                                 __builtin_fmaxf(red[2], red[3]));
    pmax = __builtin_fmaxf(pmax, __shfl_xor(pmax, 32));
    const float Mnew = __builtin_fmaxf(M, pmax);
    const float scale = __builtin_amdgcn_exp2f((M - Mnew) * CEXP);

#pragma unroll
    for (int t = 0; t < 2; ++t) {
#pragma unroll
      for (int r = 0; r < 16; ++r)
        st[t][r] = __builtin_amdgcn_exp2f((st[t][r] - Mnew) * CEXP);
    }
    if (!fast) {  // force masked p to exactly 0 (handles all-masked tiles)
      const long long qlim = qstart + (long long)(q0 + w * 32 + ql);
#pragma unroll
      for (int t = 0; t < 2; ++t) {
#pragma unroll
        for (int r = 0; r < 16; ++r) {
          int nl = t * 32 + (r & 3) + 8 * (r >> 2) + 4 * hi;
          bool ok = (mskSh[nl] != 0) && ((long long)(kv0 + nl) <= qlim);
          if (!ok) st[t][r] = 0.0f;
        }
      }
    }

    f32x16 sx;
#pragma unroll
    for (int r = 0; r < 16; ++r) sx[r] = st[0][r] + st[1][r];
#pragma unroll
    for (int r = 0; r < 8; ++r) sx[r] = sx[r] + sx[r + 8];
#pragma unroll
    for (int r = 0; r < 4; ++r) sx[r] = sx[r] + sx[r + 4];
    float ps = (sx[0] + sx[1]) + (sx[2] + sx[3]);
    ps += __shfl_xor(ps, 32);
    L = L * scale + ps;

    // ---- rescale O by exp((Mold-Mnew)*c), per q-row = per acc reg ----
    if (!__all(Mnew == M)) {
#pragma unroll
      for (int r = 0; r < 16; ++r) {
        float sc = __shfl(scale, (r & 3) + 8 * (r >> 2) + 4 * hi);
        acc[0][r] *= sc; acc[1][r] *= sc; acc[2][r] *= sc; acc[3][r] *= sc;
      }
    }
    M = Mnew;

    // ---- P -> bf16 A-frags: cvt_pk pairs + permlane32_swap (T12) ----
    short8 pa[4];
#pragma unroll
    for (int ks = 0; ks < 4; ++ks) {
      const int t = ks >> 1;
      const int m8 = (ks & 1) * 8;
      unsigned int X0, X1, Y0, Y1;
      asm("v_cvt_pk_bf16_f32 %0, %1, %2" : "=v"(X0) : "v"(st[t][m8 + 0]), "v"(st[t][m8 + 1]));
      asm("v_cvt_pk_bf16_f32 %0, %1, %2" : "=v"(X1) : "v"(st[t][m8 + 2]), "v"(st[t][m8 + 3]));
      asm("v_cvt_pk_bf16_f32 %0, %1, %2" : "=v"(Y0) : "v"(st[t][m8 + 4]), "v"(st[t][m8 + 5]));
      asm("v_cvt_pk_bf16_f32 %0, %1, %2" : "=v"(Y1) : "v"(st[t][m8 + 6]), "v"(st[t][m8 + 7]));
      asm("v_permlane32_swap_b32 %0, %1" : "+v"(X0), "+v"(Y0));
      asm("v_permlane32_swap_b32 %0, %1" : "+v"(X1), "+v"(Y1));
      UP4 P;
      P.u[0] = X0; P.u[1] = X1; P.u[2] = Y0; P.u[3] = Y1;
      pa[ks] = P.v;
    }

    // ---- PV: out[q][d] += P[q][k] * Vd[k][d]; V B-frags via ds_read_b64_tr_b16 ----
#pragma unroll
    for (int n = 0; n < 4; ++n) {
      unsigned long long t0[4], t1[4];
#pragma unroll
      for (int ks = 0; ks < 4; ++ks) {
        unsigned int addr = vbase
          + (unsigned int)(((4 * ks + 2 * hi) * 8 + 2 * n + ((lane >> 4) & 1)) * 128)
          + (unsigned int)((lane & 15) * 8);
        asm volatile("ds_read_b64_tr_b16 %0, %1" : "=v"(t0[ks]) : "v"(addr));
        asm volatile("ds_read_b64_tr_b16 %0, %1 offset:1024" : "=v"(t1[ks]) : "v"(addr));
      }
      asm volatile("s_waitcnt lgkmcnt(0)" ::: "memory");
      __builtin_amdgcn_sched_barrier(0);   // rule 18: keep MFMAs below the wait
#pragma unroll
      for (int ks = 0; ks < 4; ++ks) {
        UV2 vb;
        vb.q[0] = t0[ks]; vb.q[1] = t1[ks];
        acc[n] = __builtin_amdgcn_mfma_f32_32x32x16_bf16(pa[ks], vb.v, acc[n], 0, 0, 0);
      }
    }
  }

  // ---- epilogue: out = acc / L ----
  if (L == 0.0f) L = 1.0f;
  float rinv = 1.0f / L;
#pragma unroll
  for (int r = 0; r < 16; ++r) {
    int cr = (r & 3) + 8 * (r >> 2) + 4 * hi;       // q row within wave tile
    float inv = __shfl(rinv, cr);
    float* op = outg + ((size_t)b * SQ + (q0 + w * 32 + cr)) * DM + h * DH + ql;
    op[0]  = acc[0][r] * inv;
    op[32] = acc[1][r] * inv;
    op[64] = acc[2][r] * inv;
    op[96] = acc[3][r] * inv;
  }
}

extern "C" void kernel_launch(void* const* d_in, const int* in_sizes, int n_in,
                              void* d_out, int out_size, void* d_ws, size_t ws_size,
                              hipStream_t stream) {
  (void)in_sizes; (void)n_in; (void)out_size; (void)d_ws; (void)ws_size;
  const float* q = (const float*)d_in[0];
  const float* k = (const float*)d_in[1];
  const float* v = (const float*)d_in[2];
  const unsigned char* mask = (const unsigned char*)d_in[3];
  const int* qs = (const int*)d_in[4];
  dim3 grid(SQ / 256, 16, 4);   // (q-tiles, heads, batch)
  dim3 block(512);
  eit3_attn<<<grid, block, 0, stream>>>(q, k, v, mask, qs, (float*)d_out);
}